// Round 12
// baseline (914.688 us; speedup 1.0000x reference)
//
#include <hip/hip_runtime.h>

// LSTMPINN fused kernel, round 12: R11 +
// (1) gemm0(t+1) fused into gemm1(t) ki0-3 (shared A-frags of h0_t): i,f half in the
//     fused window (72 MFMA per load-wait), g,o half as short phase C after pw1
//     (keeps peak regs ~248 <= 256). LSTM latency windows per t: 12 -> 8.
// (2) per-block column rotation (wvr=(wv+bx)&7) to de-phase the 256 concurrent
//     blocks' L2 weight-line requests (hot-line contention test).

typedef __attribute__((ext_vector_type(8))) short bf16x8;
typedef __attribute__((ext_vector_type(4))) float f32x4;

#define TM 64          // samples per block
#define APAD 8
#define AS (256 + APAD) // A-plane row stride in ushorts

// ws layout (ushort units), interleaved: elem(r,k): hi at base + r*2K + (k>>3)*16 + (k&7), lo at +8
#define OFF_HH0 0        // 512x128
#define OFF_L1  131072   // 512x256 (cat Wih1|Whh1)
#define OFF_D0  393216   // 256x256 (cols permuted: k<128 -> mean part)
#define OFF_D1  524288
#define OFF_D2  655360
#define OFF_OUT 786432   // 16x256 (rows 4..15 zero)

__device__ __forceinline__ unsigned short f2bf(float x) {
  union { float f; unsigned u; } v; v.f = x;
  unsigned r = v.u + 0x7fffu + ((v.u >> 16) & 1u);   // RNE
  return (unsigned short)(r >> 16);
}
__device__ __forceinline__ float bf2f(unsigned short b) {
  union { unsigned u; float f; } v; v.u = ((unsigned)b) << 16; return v.f;
}
__device__ __forceinline__ float sigm(float v) { return 1.f / (1.f + __expf(-v)); }
__device__ __forceinline__ float tanh_(float v) { return 1.f - 2.f / (__expf(2.f * v) + 1.f); }

// ---------------- prep: split weights into interleaved bf16 hi/lo chunks ---------------
__global__ void prep_k(const float* __restrict__ Whh0, const float* __restrict__ Wih1,
                       const float* __restrict__ Whh1, const float* __restrict__ Wd0,
                       const float* __restrict__ Wd1, const float* __restrict__ Wd2,
                       const float* __restrict__ Wout, unsigned short* __restrict__ ws) {
  int id = blockIdx.x * 256 + threadIdx.x;
  if (id >= 397312) return;
  float w; int base, r, k, K;
  if (id < 65536) {                       // W_hh_l0 [512][128]
    r = id >> 7; k = id & 127; K = 128; base = OFF_HH0; w = Whh0[id];
  } else if (id < 196608) {               // B_l1 [512][256] = cat(Wih1, Whh1)
    int i = id - 65536; r = i >> 8; k = i & 255; K = 256; base = OFF_L1;
    w = (k < 128) ? Wih1[(r << 7) + k] : Whh1[(r << 7) + k - 128];
  } else if (id < 262144) {               // Bd0 [256][256], permute: our k<128 = mean
    int i = id - 196608; r = i >> 8; k = i & 255; K = 256; base = OFF_D0;
    w = Wd0[(r << 8) + ((k < 128) ? k + 128 : k - 128)];
  } else if (id < 327680) {               // Bd1
    int i = id - 262144; r = i >> 8; k = i & 255; K = 256; base = OFF_D1; w = Wd1[i];
  } else if (id < 393216) {               // Bd2
    int i = id - 327680; r = i >> 8; k = i & 255; K = 256; base = OFF_D2; w = Wd2[i];
  } else {                                // Bout [16][256], rows >=4 zero
    int i = id - 393216; r = i >> 8; k = i & 255; K = 256; base = OFF_OUT;
    w = (r < 4) ? Wout[(r << 8) + k] : 0.f;
  }
  unsigned short hi = f2bf(w);
  unsigned short lo = f2bf(w - bf2f(hi));
  int off = base + r * 2 * K + ((k >> 3) << 4) + (k & 7);
  ws[off] = hi;
  ws[off + 8] = lo;
}

// ------- dense-path split-bf16 GEMM (R11 form: compile-time KITERS, term-major) -------
template <int NT, int KITERS, int UNROLL>
__device__ __forceinline__ void gemm_frag(const unsigned short* __restrict__ B,
                                          const int ldB2, const int* cols,
                                          const unsigned short (*Ah)[AS],
                                          const unsigned short (*Al)[AS],
                                          int l16, int quad, f32x4 (&acc)[4][4]) {
  const unsigned short* bp[NT];
#pragma unroll
  for (int n = 0; n < NT; ++n)
    bp[n] = B + (size_t)(cols[n] + l16) * ldB2 + quad * 16;
  const unsigned short* aph = &Ah[l16][quad * 8];
  const unsigned short* apl = &Al[l16][quad * 8];
#pragma unroll UNROLL
  for (int ki = 0; ki < KITERS; ++ki) {
    bf16x8 bh[NT], bl[NT];
#pragma unroll
    for (int n = 0; n < NT; ++n) {
      bh[n] = *(const bf16x8*)(bp[n]);
      bl[n] = *(const bf16x8*)(bp[n] + 8);
      bp[n] += 64;
    }
    bf16x8 afh[4], afl[4];
#pragma unroll
    for (int m = 0; m < 4; ++m) {
      afh[m] = *(const bf16x8*)(aph + m * 16 * AS);
      afl[m] = *(const bf16x8*)(apl + m * 16 * AS);
    }
#pragma unroll
    for (int n = 0; n < NT; ++n)
#pragma unroll
      for (int m = 0; m < 4; ++m)
        acc[m][n] = __builtin_amdgcn_mfma_f32_16x16x32_bf16(afh[m], bh[n], acc[m][n], 0, 0, 0);
#pragma unroll
    for (int n = 0; n < NT; ++n)
#pragma unroll
      for (int m = 0; m < 4; ++m)
        acc[m][n] = __builtin_amdgcn_mfma_f32_16x16x32_bf16(afl[m], bh[n], acc[m][n], 0, 0, 0);
#pragma unroll
    for (int n = 0; n < NT; ++n)
#pragma unroll
      for (int m = 0; m < 4; ++m)
        acc[m][n] = __builtin_amdgcn_mfma_f32_16x16x32_bf16(afh[m], bl[n], acc[m][n], 0, 0, 0);
    aph += 32;
    apl += 32;
  }
}

// ---------------- main fused kernel: 1 block = 64 samples, 8 waves, full network -------
__global__ __launch_bounds__(512, 1) void fused_k(
    const float* __restrict__ x, const float* __restrict__ y,
    const float* __restrict__ Wih0, const float* __restrict__ b0,
    const float* __restrict__ b1, const float* __restrict__ bd0,
    const float* __restrict__ bd1, const float* __restrict__ bd2,
    const float* __restrict__ bout, const unsigned short* __restrict__ wsu,
    float* __restrict__ out) {
  // Double-buffered activation planes. Plane p=t&1 holds [h0_t | h1_{t-1}] for iter t.
  __shared__ unsigned short Ahi[2][TM][AS];
  __shared__ unsigned short Alo[2][TM][AS];
  __shared__ float feats[6][TM];

  const int tid = threadIdx.x;
  const int wv = tid >> 6;     // wave 0..7
  const int lane = tid & 63;
  const int quad = lane >> 4;  // 0..3
  const int l16 = lane & 15;
  const int bx = blockIdx.x;
  const int wvr = (wv + bx) & 7;   // rotated wave slot (L2 de-phasing)
  const int u = 16 * wvr + l16;    // this lane's LSTM unit (0..127)
  const int sb = bx * TM;

  if (tid < TM) {
    float xn = 2.f * x[sb + tid] - 1.f;
    float yn = 2.f * y[sb + tid] - 1.f;
    feats[0][tid] = xn; feats[1][tid] = yn; feats[2][tid] = xn + yn;
    feats[3][tid] = xn - yn; feats[4][tid] = xn * yn; feats[5][tid] = xn * xn + yn * yn;
  }

  // per-lane weights/biases straight from global (L1/L2-hot): gate n -> col 128n+u
  float wih0v[4], b0v[4], b1v[4];
#pragma unroll
  for (int n = 0; n < 4; ++n) {
    wih0v[n] = Wih0[128 * n + u]; b0v[n] = b0[128 * n + u]; b1v[n] = b1[128 * n + u];
  }

  // per-lane state: [m][r] -> sample s=16m+4quad+r, unit u
  float c0[4][4], c1[4][4], meanh[4][4];
#pragma unroll
  for (int m = 0; m < 4; ++m)
#pragma unroll
    for (int r = 0; r < 4; ++r) { c0[m][r] = 0.f; c1[m][r] = 0.f; meanh[m][r] = 0.f; }

  int colsL[4];  // gate-type n -> col block (rotated)
#pragma unroll
  for (int n = 0; n < 4; ++n) colsL[n] = 128 * n + 16 * wvr;

  __syncthreads();  // feats visible

  // ---- prologue: pw0(t=0): gates = x_0*Wih0 + b0 (no GEMM), h0_0 -> plane 0 ----
#pragma unroll
  for (int m = 0; m < 4; ++m)
#pragma unroll
    for (int r = 0; r < 4; ++r) {
      const float xf = feats[0][16 * m + 4 * quad + r];
      float iv = sigm(xf * wih0v[0] + b0v[0]);
      float gv = tanh_(xf * wih0v[2] + b0v[2]);
      float ov = sigm(xf * wih0v[3] + b0v[3]);
      float cc = iv * gv;                // c was 0: f*0 + i*g
      c0[m][r] = cc;
      float h = ov * tanh_(cc);
      const int s = 16 * m + 4 * quad + r;
      unsigned short hh = f2bf(h);
      Ahi[0][s][u] = hh;
      Alo[0][s][u] = f2bf(h - bf2f(hh));
    }

  // ---- main loop: one barrier per t. Plane p = t&1 holds [h0_t | h1_{t-1}]. ----
#pragma unroll 1
  for (int t = 0; t < 6; ++t) {
    const int p = t & 1;
    const int pn = p ^ 1;
    const bool hasG0 = (t < 5);
    __syncthreads();  // h0_t (and h1_{t-1}) visible in plane p; WAR for plane pn writes

    f32x4 acc1[4][4];   // gemm1 accumulators
#pragma unroll
    for (int m = 0; m < 4; ++m)
#pragma unroll
      for (int n = 0; n < 4; ++n)
#pragma unroll
        for (int r = 0; r < 4; ++r) acc1[m][n][r] = b1v[n];
    f32x4 a0if[4][2];   // gemm0 i,f accumulators (fused into phase A)
    if (hasG0) {
#pragma unroll
      for (int m = 0; m < 4; ++m)
#pragma unroll
        for (int r = 0; r < 4; ++r) {
          const float xf = feats[t + 1][16 * m + 4 * quad + r];
          a0if[m][0][r] = xf * wih0v[0] + b0v[0];
          a0if[m][1][r] = xf * wih0v[1] + b0v[1];
        }
    }

    // ---- phase A: ki 0..3 — gemm1 (B_l1, k=h0_t) fused with gemm0 i,f (B_hh0) ----
    {
      const unsigned short* aph = &Ahi[p][l16][quad * 8];
      const unsigned short* apl = &Alo[p][l16][quad * 8];
      const unsigned short* b1b = wsu + OFF_L1 + (size_t)l16 * 512 + quad * 16;
      const unsigned short* b0b = wsu + OFF_HH0 + (size_t)l16 * 256 + quad * 16;
#pragma unroll 1
      for (int ki = 0; ki < 4; ++ki) {
        const int koff = ki * 64;
        bf16x8 b1h[4], b1l[4];
#pragma unroll
        for (int n = 0; n < 4; ++n) {
          const unsigned short* q = b1b + colsL[n] * 512 + koff;
          b1h[n] = *(const bf16x8*)q;
          b1l[n] = *(const bf16x8*)(q + 8);
        }
        bf16x8 b0h[2], b0l[2];
        if (hasG0) {
#pragma unroll
          for (int n = 0; n < 2; ++n) {
            const unsigned short* q = b0b + colsL[n] * 256 + koff;
            b0h[n] = *(const bf16x8*)q;
            b0l[n] = *(const bf16x8*)(q + 8);
          }
        }
        bf16x8 afh[4], afl[4];
#pragma unroll
        for (int m = 0; m < 4; ++m) {
          afh[m] = *(const bf16x8*)(aph + m * 16 * AS);
          afl[m] = *(const bf16x8*)(apl + m * 16 * AS);
        }
#pragma unroll
        for (int n = 0; n < 4; ++n)
#pragma unroll
          for (int m = 0; m < 4; ++m)
            acc1[m][n] = __builtin_amdgcn_mfma_f32_16x16x32_bf16(afh[m], b1h[n], acc1[m][n], 0, 0, 0);
#pragma unroll
        for (int n = 0; n < 4; ++n)
#pragma unroll
          for (int m = 0; m < 4; ++m)
            acc1[m][n] = __builtin_amdgcn_mfma_f32_16x16x32_bf16(afl[m], b1h[n], acc1[m][n], 0, 0, 0);
#pragma unroll
        for (int n = 0; n < 4; ++n)
#pragma unroll
          for (int m = 0; m < 4; ++m)
            acc1[m][n] = __builtin_amdgcn_mfma_f32_16x16x32_bf16(afh[m], b1l[n], acc1[m][n], 0, 0, 0);
        if (hasG0) {
#pragma unroll
          for (int n = 0; n < 2; ++n)
#pragma unroll
            for (int m = 0; m < 4; ++m) {
              a0if[m][n] = __builtin_amdgcn_mfma_f32_16x16x32_bf16(afh[m], b0h[n], a0if[m][n], 0, 0, 0);
              a0if[m][n] = __builtin_amdgcn_mfma_f32_16x16x32_bf16(afl[m], b0h[n], a0if[m][n], 0, 0, 0);
              a0if[m][n] = __builtin_amdgcn_mfma_f32_16x16x32_bf16(afh[m], b0l[n], a0if[m][n], 0, 0, 0);
            }
        }
        aph += 32;
        apl += 32;
      }
    }

    // ---- phase B: t>0: gemm1 ki 4..7 (k = h1_{t-1} part of plane p) ----
    if (t > 0) {
      const unsigned short* aph = &Ahi[p][l16][128 + quad * 8];
      const unsigned short* apl = &Alo[p][l16][128 + quad * 8];
      const unsigned short* b1b = wsu + OFF_L1 + (size_t)l16 * 512 + quad * 16;
#pragma unroll 1
      for (int ki = 4; ki < 8; ++ki) {
        const int koff = ki * 64;
        bf16x8 b1h[4], b1l[4];
#pragma unroll
        for (int n = 0; n < 4; ++n) {
          const unsigned short* q = b1b + colsL[n] * 512 + koff;
          b1h[n] = *(const bf16x8*)q;
          b1l[n] = *(const bf16x8*)(q + 8);
        }
        bf16x8 afh[4], afl[4];
#pragma unroll
        for (int m = 0; m < 4; ++m) {
          afh[m] = *(const bf16x8*)(aph + m * 16 * AS);
          afl[m] = *(const bf16x8*)(apl + m * 16 * AS);
        }
#pragma unroll
        for (int n = 0; n < 4; ++n)
#pragma unroll
          for (int m = 0; m < 4; ++m)
            acc1[m][n] = __builtin_amdgcn_mfma_f32_16x16x32_bf16(afh[m], b1h[n], acc1[m][n], 0, 0, 0);
#pragma unroll
        for (int n = 0; n < 4; ++n)
#pragma unroll
          for (int m = 0; m < 4; ++m)
            acc1[m][n] = __builtin_amdgcn_mfma_f32_16x16x32_bf16(afl[m], b1h[n], acc1[m][n], 0, 0, 0);
#pragma unroll
        for (int n = 0; n < 4; ++n)
#pragma unroll
          for (int m = 0; m < 4; ++m)
            acc1[m][n] = __builtin_amdgcn_mfma_f32_16x16x32_bf16(afh[m], b1l[n], acc1[m][n], 0, 0, 0);
        aph += 32;
        apl += 32;
      }
    }

    // ---- pw1(t): h1_t -> plane pn [128:256); mean at t=5 -> plane pn [0:128) ----
#pragma unroll
    for (int m = 0; m < 4; ++m)
#pragma unroll
      for (int r = 0; r < 4; ++r) {
        float iv = sigm(acc1[m][0][r]);
        float fv = sigm(acc1[m][1][r]);
        float gv = tanh_(acc1[m][2][r]);
        float ov = sigm(acc1[m][3][r]);
        float cc = fv * c1[m][r] + iv * gv;
        c1[m][r] = cc;
        float h = ov * tanh_(cc);
        const int s = 16 * m + 4 * quad + r;
        unsigned short hh = f2bf(h);
        Ahi[pn][s][128 + u] = hh;
        Alo[pn][s][128 + u] = f2bf(h - bf2f(hh));
        float mn = meanh[m][r] + h;
        meanh[m][r] = mn;
        if (t == 5) {
          mn *= (1.f / 6.f);
          unsigned short mh = f2bf(mn);
          Ahi[pn][s][u] = mh;
          Alo[pn][s][u] = f2bf(mn - bf2f(mh));
        }
      }

    // ---- phase C + pw0: gemm0 g,o half, then the layer-0 pointwise ----
    if (hasG0) {
      f32x4 a0go[4][2];
#pragma unroll
      for (int m = 0; m < 4; ++m)
#pragma unroll
        for (int r = 0; r < 4; ++r) {
          const float xf = feats[t + 1][16 * m + 4 * quad + r];
          a0go[m][0][r] = xf * wih0v[2] + b0v[2];
          a0go[m][1][r] = xf * wih0v[3] + b0v[3];
        }
      {
        const unsigned short* aph = &Ahi[p][l16][quad * 8];
        const unsigned short* apl = &Alo[p][l16][quad * 8];
        const unsigned short* b0b = wsu + OFF_HH0 + (size_t)l16 * 256 + quad * 16;
#pragma unroll 1
        for (int ki = 0; ki < 4; ++ki) {
          const int koff = ki * 64;
          bf16x8 b0h[2], b0l[2];
#pragma unroll
          for (int n = 0; n < 2; ++n) {
            const unsigned short* q = b0b + colsL[2 + n] * 256 + koff;
            b0h[n] = *(const bf16x8*)q;
            b0l[n] = *(const bf16x8*)(q + 8);
          }
          bf16x8 afh[4], afl[4];
#pragma unroll
          for (int m = 0; m < 4; ++m) {
            afh[m] = *(const bf16x8*)(aph + m * 16 * AS);
            afl[m] = *(const bf16x8*)(apl + m * 16 * AS);
          }
#pragma unroll
          for (int n = 0; n < 2; ++n)
#pragma unroll
            for (int m = 0; m < 4; ++m) {
              a0go[m][n] = __builtin_amdgcn_mfma_f32_16x16x32_bf16(afh[m], b0h[n], a0go[m][n], 0, 0, 0);
              a0go[m][n] = __builtin_amdgcn_mfma_f32_16x16x32_bf16(afl[m], b0h[n], a0go[m][n], 0, 0, 0);
              a0go[m][n] = __builtin_amdgcn_mfma_f32_16x16x32_bf16(afh[m], b0l[n], a0go[m][n], 0, 0, 0);
            }
          aph += 32;
          apl += 32;
        }
      }
      // pw0(t+1): h0_{t+1} -> plane pn [0:128)
#pragma unroll
      for (int m = 0; m < 4; ++m)
#pragma unroll
        for (int r = 0; r < 4; ++r) {
          float iv = sigm(a0if[m][0][r]);
          float fv = sigm(a0if[m][1][r]);
          float gv = tanh_(a0go[m][0][r]);
          float ov = sigm(a0go[m][1][r]);
          float cc = fv * c0[m][r] + iv * gv;
          c0[m][r] = cc;
          float h = ov * tanh_(cc);
          const int s = 16 * m + 4 * quad + r;
          unsigned short hh = f2bf(h);
          Ahi[pn][s][u] = hh;
          Alo[pn][s][u] = f2bf(h - bf2f(hh));
        }
    }
  }

  // ---- dense head: 3 layers; L0 reads plane0=[mean|last] (t=5 wrote pn=0) ----
  const int wvd = (wv + bx) & 7;   // rotated dense slot
  int colsD[2];
  colsD[0] = 32 * wvd; colsD[1] = 32 * wvd + 16;

#pragma unroll 1
  for (int layer = 0; layer < 3; ++layer) {
    const int base = (layer == 0) ? OFF_D0 : ((layer == 1) ? OFF_D1 : OFF_D2);
    const float* bd = (layer == 0) ? bd0 : ((layer == 1) ? bd1 : bd2);
    const int sp = layer & 1;   // read plane 0,1,0
    const int dp = sp ^ 1;
    float bdv[2];
#pragma unroll
    for (int n = 0; n < 2; ++n) bdv[n] = bd[colsD[n] + l16];
    f32x4 acc[4][4];
#pragma unroll
    for (int m = 0; m < 4; ++m)
#pragma unroll
      for (int n = 0; n < 2; ++n)
#pragma unroll
        for (int r = 0; r < 4; ++r) acc[m][n][r] = bdv[n];
    __syncthreads();  // prev writes visible; prev reads of dp done (WAR)
    gemm_frag<2, 8, 2>(wsu + base, 512, colsD, Ahi[sp], Alo[sp], l16, quad, acc);
#pragma unroll
    for (int m = 0; m < 4; ++m)
#pragma unroll
      for (int r = 0; r < 4; ++r) {
        const int s = 16 * m + 4 * quad + r;
#pragma unroll
        for (int n = 0; n < 2; ++n) {
          const int col = colsD[n] + l16;
          float a = tanh_(acc[m][n][r]);
          unsigned short ah = f2bf(a);
          Ahi[dp][s][col] = ah;
          Alo[dp][s][col] = f2bf(a - bf2f(ah));
        }
      }
  }
  __syncthreads();

  // ---- output layer: waves 0..3 handle m-tile wv (16 samples); read plane 1 ----
  if (wv < 4) {
    f32x4 oacc = {0.f, 0.f, 0.f, 0.f};
    const unsigned short* bp = wsu + OFF_OUT + (size_t)l16 * 512 + quad * 16;
    const unsigned short* aph = &Ahi[1][16 * wv + l16][quad * 8];
    const unsigned short* apl = &Alo[1][16 * wv + l16][quad * 8];
#pragma unroll 1
    for (int ki = 0; ki < 8; ++ki) {
      bf16x8 ah = *(const bf16x8*)aph;
      bf16x8 al = *(const bf16x8*)apl;
      bf16x8 bh = *(const bf16x8*)bp;
      bf16x8 bl = *(const bf16x8*)(bp + 8);
      oacc = __builtin_amdgcn_mfma_f32_16x16x32_bf16(ah, bh, oacc, 0, 0, 0);
      oacc = __builtin_amdgcn_mfma_f32_16x16x32_bf16(al, bh, oacc, 0, 0, 0);
      oacc = __builtin_amdgcn_mfma_f32_16x16x32_bf16(ah, bl, oacc, 0, 0, 0);
      aph += 32; apl += 32; bp += 64;
    }
    float bo = (l16 < 4) ? bout[l16] : 0.f;
#pragma unroll
    for (int r = 0; r < 4; ++r) {
      if (l16 < 4) {
        int s = sb + 16 * wv + 4 * quad + r;
        out[s * 4 + l16] = oacc[r] + bo;
      }
    }
  }
}

extern "C" void kernel_launch(void* const* d_in, const int* in_sizes, int n_in,
                              void* d_out, int out_size, void* d_ws, size_t ws_size,
                              hipStream_t stream) {
  (void)in_sizes; (void)n_in; (void)out_size; (void)ws_size;
  const float* x    = (const float*)d_in[0];
  const float* y    = (const float*)d_in[1];
  const float* Wih0 = (const float*)d_in[2];
  const float* Whh0 = (const float*)d_in[3];
  const float* b0   = (const float*)d_in[4];
  const float* Wih1 = (const float*)d_in[5];
  const float* Whh1 = (const float*)d_in[6];
  const float* b1   = (const float*)d_in[7];
  const float* Wd0  = (const float*)d_in[8];
  const float* bd0  = (const float*)d_in[9];
  const float* Wd1  = (const float*)d_in[10];
  const float* bd1  = (const float*)d_in[11];
  const float* Wd2  = (const float*)d_in[12];
  const float* bd2  = (const float*)d_in[13];
  const float* Wout = (const float*)d_in[14];
  const float* bout = (const float*)d_in[15];
  unsigned short* ws = (unsigned short*)d_ws;
  float* out = (float*)d_out;

  prep_k<<<dim3(1552), dim3(256), 0, stream>>>(Whh0, Wih1, Whh1, Wd0, Wd1, Wd2, Wout, ws);
  fused_k<<<dim3(65536 / TM), dim3(512), 0, stream>>>(x, y, Wih0, b0, b1, bd0, bd1, bd2,
                                                      bout, ws, out);
}

// Round 13
// 673.352 us; speedup vs baseline: 1.3584x; 1.3584x over previous
//
#include <hip/hip_runtime.h>

// LSTMPINN fused kernel, round 13: R11 base + precision-margin spend:
// LSTM GEMMs (gemm0/gemm1) use 2-term split (Ah*Bh + Al*Bh) with hi-only
// row-major B (halves B bytes/window, -28% MFMA, -32 transient regs).
// Dense head + output keep full 3-term (largest error contributors).

typedef __attribute__((ext_vector_type(8))) short bf16x8;
typedef __attribute__((ext_vector_type(4))) float f32x4;

#define TM 64          // samples per block
#define APAD 8
#define AS (256 + APAD) // A-plane row stride in ushorts

// ws layout (ushort units):
// LSTM B: hi-only row-major. Dense/out: interleaved hi/lo per 8-elem chunk.
#define OFF_HH0 0        // 512x128 hi-only
#define OFF_L1  65536    // 512x256 hi-only (cat Wih1|Whh1)
#define OFF_D0  196608   // 256x256 interleaved (cols permuted: k<128 -> mean)
#define OFF_D1  327680
#define OFF_D2  458752
#define OFF_OUT 589824   // 16x256 interleaved (rows 4..15 zero)

__device__ __forceinline__ unsigned short f2bf(float x) {
  union { float f; unsigned u; } v; v.f = x;
  unsigned r = v.u + 0x7fffu + ((v.u >> 16) & 1u);   // RNE
  return (unsigned short)(r >> 16);
}
__device__ __forceinline__ float bf2f(unsigned short b) {
  union { unsigned u; float f; } v; v.u = ((unsigned)b) << 16; return v.f;
}
__device__ __forceinline__ float sigm(float v) { return 1.f / (1.f + __expf(-v)); }
__device__ __forceinline__ float tanh_(float v) { return 1.f - 2.f / (__expf(2.f * v) + 1.f); }

// ---------------- prep: LSTM hi-only row-major; dense interleaved hi/lo ---------------
__global__ void prep_k(const float* __restrict__ Whh0, const float* __restrict__ Wih1,
                       const float* __restrict__ Whh1, const float* __restrict__ Wd0,
                       const float* __restrict__ Wd1, const float* __restrict__ Wd2,
                       const float* __restrict__ Wout, unsigned short* __restrict__ ws) {
  int id = blockIdx.x * 256 + threadIdx.x;
  if (id >= 397312) return;
  if (id < 65536) {                       // W_hh_l0 [512][128] hi-only
    ws[OFF_HH0 + id] = f2bf(Whh0[id]);
    return;
  }
  if (id < 196608) {                      // B_l1 [512][256] = cat(Wih1,Whh1) hi-only
    int i = id - 65536;
    int r = i >> 8, k = i & 255;
    float w = (k < 128) ? Wih1[(r << 7) + k] : Whh1[(r << 7) + k - 128];
    ws[OFF_L1 + i] = f2bf(w);
    return;
  }
  float w; int base, r, k;
  if (id < 262144) {                      // Bd0 [256][256], permute: our k<128 = mean
    int i = id - 196608; r = i >> 8; k = i & 255; base = OFF_D0;
    w = Wd0[(r << 8) + ((k < 128) ? k + 128 : k - 128)];
  } else if (id < 327680) {               // Bd1
    int i = id - 262144; r = i >> 8; k = i & 255; base = OFF_D1; w = Wd1[i];
  } else if (id < 393216) {               // Bd2
    int i = id - 327680; r = i >> 8; k = i & 255; base = OFF_D2; w = Wd2[i];
  } else {                                // Bout [16][256], rows >=4 zero
    int i = id - 393216; r = i >> 8; k = i & 255; base = OFF_OUT;
    w = (r < 4) ? Wout[(r << 8) + k] : 0.f;
  }
  unsigned short hi = f2bf(w);
  unsigned short lo = f2bf(w - bf2f(hi));
  int off = base + r * 512 + ((k >> 3) << 4) + (k & 7);
  ws[off] = hi;
  ws[off + 8] = lo;
}

// ------- 2-term split GEMM (LSTM): B hi-only row-major, acc += (Ah+Al)*Bh -------
template <int NT, int KITERS, int UNROLL>
__device__ __forceinline__ void gemm2t(const unsigned short* __restrict__ B,
                                       const int ldB, const int* cols,
                                       const unsigned short (*Ah)[AS],
                                       const unsigned short (*Al)[AS],
                                       int l16, int quad, f32x4 (&acc)[4][4]) {
  const unsigned short* bp[NT];
#pragma unroll
  for (int n = 0; n < NT; ++n)
    bp[n] = B + (size_t)(cols[n] + l16) * ldB + quad * 8;
  const unsigned short* aph = &Ah[l16][quad * 8];
  const unsigned short* apl = &Al[l16][quad * 8];
#pragma unroll UNROLL
  for (int ki = 0; ki < KITERS; ++ki) {
    bf16x8 bh[NT];
#pragma unroll
    for (int n = 0; n < NT; ++n) {
      bh[n] = *(const bf16x8*)(bp[n]);
      bp[n] += 32;
    }
    bf16x8 afh[4], afl[4];
#pragma unroll
    for (int m = 0; m < 4; ++m) {
      afh[m] = *(const bf16x8*)(aph + m * 16 * AS);
      afl[m] = *(const bf16x8*)(apl + m * 16 * AS);
    }
#pragma unroll
    for (int n = 0; n < NT; ++n)
#pragma unroll
      for (int m = 0; m < 4; ++m)
        acc[m][n] = __builtin_amdgcn_mfma_f32_16x16x32_bf16(afh[m], bh[n], acc[m][n], 0, 0, 0);
#pragma unroll
    for (int n = 0; n < NT; ++n)
#pragma unroll
      for (int m = 0; m < 4; ++m)
        acc[m][n] = __builtin_amdgcn_mfma_f32_16x16x32_bf16(afl[m], bh[n], acc[m][n], 0, 0, 0);
    aph += 32;
    apl += 32;
  }
}

// ------- 3-term split GEMM (dense): interleaved hi/lo B (R11 form) -------
template <int NT, int KITERS, int UNROLL>
__device__ __forceinline__ void gemm3t(const unsigned short* __restrict__ B,
                                       const int ldB2, const int* cols,
                                       const unsigned short (*Ah)[AS],
                                       const unsigned short (*Al)[AS],
                                       int l16, int quad, f32x4 (&acc)[4][4]) {
  const unsigned short* bp[NT];
#pragma unroll
  for (int n = 0; n < NT; ++n)
    bp[n] = B + (size_t)(cols[n] + l16) * ldB2 + quad * 16;
  const unsigned short* aph = &Ah[l16][quad * 8];
  const unsigned short* apl = &Al[l16][quad * 8];
#pragma unroll UNROLL
  for (int ki = 0; ki < KITERS; ++ki) {
    bf16x8 bh[NT], bl[NT];
#pragma unroll
    for (int n = 0; n < NT; ++n) {
      bh[n] = *(const bf16x8*)(bp[n]);
      bl[n] = *(const bf16x8*)(bp[n] + 8);
      bp[n] += 64;
    }
    bf16x8 afh[4], afl[4];
#pragma unroll
    for (int m = 0; m < 4; ++m) {
      afh[m] = *(const bf16x8*)(aph + m * 16 * AS);
      afl[m] = *(const bf16x8*)(apl + m * 16 * AS);
    }
#pragma unroll
    for (int n = 0; n < NT; ++n)
#pragma unroll
      for (int m = 0; m < 4; ++m)
        acc[m][n] = __builtin_amdgcn_mfma_f32_16x16x32_bf16(afh[m], bh[n], acc[m][n], 0, 0, 0);
#pragma unroll
    for (int n = 0; n < NT; ++n)
#pragma unroll
      for (int m = 0; m < 4; ++m)
        acc[m][n] = __builtin_amdgcn_mfma_f32_16x16x32_bf16(afl[m], bh[n], acc[m][n], 0, 0, 0);
#pragma unroll
    for (int n = 0; n < NT; ++n)
#pragma unroll
      for (int m = 0; m < 4; ++m)
        acc[m][n] = __builtin_amdgcn_mfma_f32_16x16x32_bf16(afh[m], bl[n], acc[m][n], 0, 0, 0);
    aph += 32;
    apl += 32;
  }
}

// ---------------- main fused kernel: 1 block = 64 samples, 8 waves, full network -------
__global__ __launch_bounds__(512, 1) void fused_k(
    const float* __restrict__ x, const float* __restrict__ y,
    const float* __restrict__ Wih0, const float* __restrict__ b0,
    const float* __restrict__ b1, const float* __restrict__ bd0,
    const float* __restrict__ bd1, const float* __restrict__ bd2,
    const float* __restrict__ bout, const unsigned short* __restrict__ wsu,
    float* __restrict__ out) {
  // Double-buffered activation planes. Plane p=t&1 holds [h0_t | h1_{t-1}] for iter t.
  __shared__ unsigned short Ahi[2][TM][AS];
  __shared__ unsigned short Alo[2][TM][AS];
  __shared__ float feats[6][TM];

  const int tid = threadIdx.x;
  const int wv = tid >> 6;     // wave 0..7
  const int lane = tid & 63;
  const int quad = lane >> 4;  // 0..3
  const int l16 = lane & 15;
  const int u = 16 * wv + l16; // this lane's LSTM unit (0..127)
  const int sb = blockIdx.x * TM;

  if (tid < TM) {
    float xn = 2.f * x[sb + tid] - 1.f;
    float yn = 2.f * y[sb + tid] - 1.f;
    feats[0][tid] = xn; feats[1][tid] = yn; feats[2][tid] = xn + yn;
    feats[3][tid] = xn - yn; feats[4][tid] = xn * yn; feats[5][tid] = xn * xn + yn * yn;
  }

  // per-lane weights/biases straight from global (L1/L2-hot): gate n -> col 128n+u
  float wih0v[4], b0v[4], b1v[4];
#pragma unroll
  for (int n = 0; n < 4; ++n) {
    wih0v[n] = Wih0[128 * n + u]; b0v[n] = b0[128 * n + u]; b1v[n] = b1[128 * n + u];
  }

  // per-lane state: [m][r] -> sample s=16m+4quad+r, unit u
  float c0[4][4], c1[4][4], meanh[4][4];
#pragma unroll
  for (int m = 0; m < 4; ++m)
#pragma unroll
    for (int r = 0; r < 4; ++r) { c0[m][r] = 0.f; c1[m][r] = 0.f; meanh[m][r] = 0.f; }

  int colsL[4];  // gate-type n -> col block
#pragma unroll
  for (int n = 0; n < 4; ++n) colsL[n] = 128 * n + 16 * wv;

  __syncthreads();  // feats visible

  f32x4 acc[4][4];

  // ---- prologue: pw0(t=0): gates = x_0*Wih0 + b0 (no GEMM), h0_0 -> plane 0 ----
#pragma unroll
  for (int m = 0; m < 4; ++m)
#pragma unroll
    for (int r = 0; r < 4; ++r) {
      const float xf = feats[0][16 * m + 4 * quad + r];
      float iv = sigm(xf * wih0v[0] + b0v[0]);
      float gv = tanh_(xf * wih0v[2] + b0v[2]);
      float ov = sigm(xf * wih0v[3] + b0v[3]);
      float cc = iv * gv;                // c was 0: f*0 + i*g
      c0[m][r] = cc;
      float h = ov * tanh_(cc);
      const int s = 16 * m + 4 * quad + r;
      unsigned short hh = f2bf(h);
      Ahi[0][s][u] = hh;
      Alo[0][s][u] = f2bf(h - bf2f(hh));
    }

  // ---- main loop: one barrier per t. Plane p = t&1 holds [h0_t | h1_{t-1}]. ----
#pragma unroll 1
  for (int t = 0; t < 6; ++t) {
    const int p = t & 1;
    const int pn = p ^ 1;
    __syncthreads();  // h0_t (and h1_{t-1}) visible in plane p; WAR for plane pn writes

    // gemm1(t): gates1 = [h0_t ; h1_{t-1}] @ [Wih1;Whh1]^T + b1   (2-term)
#pragma unroll
    for (int m = 0; m < 4; ++m)
#pragma unroll
      for (int n = 0; n < 4; ++n)
#pragma unroll
        for (int r = 0; r < 4; ++r) acc[m][n][r] = b1v[n];
    if (t == 0)
      gemm2t<4, 4, 1>(wsu + OFF_L1, 256, colsL, Ahi[p], Alo[p], l16, quad, acc);
    else
      gemm2t<4, 8, 2>(wsu + OFF_L1, 256, colsL, Ahi[p], Alo[p], l16, quad, acc);

    // pw1(t): h1_t -> plane pn [128:256); mean at t=5 -> plane pn [0:128)
#pragma unroll
    for (int m = 0; m < 4; ++m)
#pragma unroll
      for (int r = 0; r < 4; ++r) {
        float iv = sigm(acc[m][0][r]);
        float fv = sigm(acc[m][1][r]);
        float gv = tanh_(acc[m][2][r]);
        float ov = sigm(acc[m][3][r]);
        float cc = fv * c1[m][r] + iv * gv;
        c1[m][r] = cc;
        float h = ov * tanh_(cc);
        const int s = 16 * m + 4 * quad + r;
        unsigned short hh = f2bf(h);
        Ahi[pn][s][128 + u] = hh;
        Alo[pn][s][128 + u] = f2bf(h - bf2f(hh));
        float mn = meanh[m][r] + h;
        meanh[m][r] = mn;
        if (t == 5) {
          mn *= (1.f / 6.f);
          unsigned short mh = f2bf(mn);
          Ahi[pn][s][u] = mh;
          Alo[pn][s][u] = f2bf(mn - bf2f(mh));
        }
      }

    if (t < 5) {
      // gemm0(t+1): gates0 = x_{t+1}*Wih0 + b0 (C-init) + h0_t @ Whh0^T   (2-term)
#pragma unroll
      for (int m = 0; m < 4; ++m)
#pragma unroll
        for (int r = 0; r < 4; ++r) {
          const float xf = feats[t + 1][16 * m + 4 * quad + r];
#pragma unroll
          for (int n = 0; n < 4; ++n) acc[m][n][r] = xf * wih0v[n] + b0v[n];
        }
      gemm2t<4, 4, 1>(wsu + OFF_HH0, 128, colsL, Ahi[p], Alo[p], l16, quad, acc);

      // pw0(t+1): h0_{t+1} -> plane pn [0:128)
#pragma unroll
      for (int m = 0; m < 4; ++m)
#pragma unroll
        for (int r = 0; r < 4; ++r) {
          float iv = sigm(acc[m][0][r]);
          float fv = sigm(acc[m][1][r]);
          float gv = tanh_(acc[m][2][r]);
          float ov = sigm(acc[m][3][r]);
          float cc = fv * c0[m][r] + iv * gv;
          c0[m][r] = cc;
          float h = ov * tanh_(cc);
          const int s = 16 * m + 4 * quad + r;
          unsigned short hh = f2bf(h);
          Ahi[pn][s][u] = hh;
          Alo[pn][s][u] = f2bf(h - bf2f(hh));
        }
    }
  }

  // ---- dense head: 3 layers (3-term); L0 reads plane0=[mean|last] ----
  int colsD[2];
  colsD[0] = 32 * wv; colsD[1] = 32 * wv + 16;

#pragma unroll 1
  for (int layer = 0; layer < 3; ++layer) {
    const int base = (layer == 0) ? OFF_D0 : ((layer == 1) ? OFF_D1 : OFF_D2);
    const float* bd = (layer == 0) ? bd0 : ((layer == 1) ? bd1 : bd2);
    const int sp = layer & 1;   // read plane 0,1,0
    const int dp = sp ^ 1;
    float bdv[2];
#pragma unroll
    for (int n = 0; n < 2; ++n) bdv[n] = bd[colsD[n] + l16];
#pragma unroll
    for (int m = 0; m < 4; ++m)
#pragma unroll
      for (int n = 0; n < 2; ++n)
#pragma unroll
        for (int r = 0; r < 4; ++r) acc[m][n][r] = bdv[n];
    __syncthreads();  // prev writes visible; prev reads of dp done (WAR)
    gemm3t<2, 8, 2>(wsu + base, 512, colsD, Ahi[sp], Alo[sp], l16, quad, acc);
#pragma unroll
    for (int m = 0; m < 4; ++m)
#pragma unroll
      for (int r = 0; r < 4; ++r) {
        const int s = 16 * m + 4 * quad + r;
#pragma unroll
        for (int n = 0; n < 2; ++n) {
          const int col = colsD[n] + l16;
          float a = tanh_(acc[m][n][r]);
          unsigned short ah = f2bf(a);
          Ahi[dp][s][col] = ah;
          Alo[dp][s][col] = f2bf(a - bf2f(ah));
        }
      }
  }
  __syncthreads();

  // ---- output layer (3-term): waves 0..3 handle m-tile wv; read plane 1 ----
  if (wv < 4) {
    f32x4 oacc = {0.f, 0.f, 0.f, 0.f};
    const unsigned short* bp = wsu + OFF_OUT + (size_t)l16 * 512 + quad * 16;
    const unsigned short* aph = &Ahi[1][16 * wv + l16][quad * 8];
    const unsigned short* apl = &Alo[1][16 * wv + l16][quad * 8];
#pragma unroll 1
    for (int ki = 0; ki < 8; ++ki) {
      bf16x8 ah = *(const bf16x8*)aph;
      bf16x8 al = *(const bf16x8*)apl;
      bf16x8 bh = *(const bf16x8*)bp;
      bf16x8 bl = *(const bf16x8*)(bp + 8);
      oacc = __builtin_amdgcn_mfma_f32_16x16x32_bf16(ah, bh, oacc, 0, 0, 0);
      oacc = __builtin_amdgcn_mfma_f32_16x16x32_bf16(al, bh, oacc, 0, 0, 0);
      oacc = __builtin_amdgcn_mfma_f32_16x16x32_bf16(ah, bl, oacc, 0, 0, 0);
      aph += 32; apl += 32; bp += 64;
    }
    float bo = (l16 < 4) ? bout[l16] : 0.f;
#pragma unroll
    for (int r = 0; r < 4; ++r) {
      if (l16 < 4) {
        int s = sb + 16 * wv + 4 * quad + r;
        out[s * 4 + l16] = oacc[r] + bo;
      }
    }
  }
}

extern "C" void kernel_launch(void* const* d_in, const int* in_sizes, int n_in,
                              void* d_out, int out_size, void* d_ws, size_t ws_size,
                              hipStream_t stream) {
  (void)in_sizes; (void)n_in; (void)out_size; (void)ws_size;
  const float* x    = (const float*)d_in[0];
  const float* y    = (const float*)d_in[1];
  const float* Wih0 = (const float*)d_in[2];
  const float* Whh0 = (const float*)d_in[3];
  const float* b0   = (const float*)d_in[4];
  const float* Wih1 = (const float*)d_in[5];
  const float* Whh1 = (const float*)d_in[6];
  const float* b1   = (const float*)d_in[7];
  const float* Wd0  = (const float*)d_in[8];
  const float* bd0  = (const float*)d_in[9];
  const float* Wd1  = (const float*)d_in[10];
  const float* bd1  = (const float*)d_in[11];
  const float* Wd2  = (const float*)d_in[12];
  const float* bd2  = (const float*)d_in[13];
  const float* Wout = (const float*)d_in[14];
  const float* bout = (const float*)d_in[15];
  unsigned short* ws = (unsigned short*)d_ws;
  float* out = (float*)d_out;

  prep_k<<<dim3(1552), dim3(256), 0, stream>>>(Whh0, Wih1, Whh1, Wd0, Wd1, Wd2, Wout, ws);
  fused_k<<<dim3(65536 / TM), dim3(512), 0, stream>>>(x, y, Wih0, b0, b1, bd0, bd1, bd2,
                                                      bout, ws, out);
}

// Round 14
// 645.933 us; speedup vs baseline: 1.4161x; 1.0424x over previous
//
#include <hip/hip_runtime.h>

// LSTMPINN fused kernel, round 14: R13 + LSTM GEMMs to single-term (Ah*Bh, pure
// bf16 x bf16). Dense head + output keep 3-term split. Evidence: absmax has been
// pinned at exactly 1 bf16-ulp (2^-16) through all precision changes -> we are at
// the comparison floor; LSTM path demonstrably damps rounding error.
// Savings: LSTM MFMA/wave 2048->1024, A-frag LDS reads halved, Alo writes only at t=5.

typedef __attribute__((ext_vector_type(8))) short bf16x8;
typedef __attribute__((ext_vector_type(4))) float f32x4;

#define TM 64          // samples per block
#define APAD 8
#define AS (256 + APAD) // A-plane row stride in ushorts

// ws layout (ushort units):
// LSTM B: hi-only row-major. Dense/out: interleaved hi/lo per 8-elem chunk.
#define OFF_HH0 0        // 512x128 hi-only
#define OFF_L1  65536    // 512x256 hi-only (cat Wih1|Whh1)
#define OFF_D0  196608   // 256x256 interleaved (cols permuted: k<128 -> mean)
#define OFF_D1  327680
#define OFF_D2  458752
#define OFF_OUT 589824   // 16x256 interleaved (rows 4..15 zero)

__device__ __forceinline__ unsigned short f2bf(float x) {
  union { float f; unsigned u; } v; v.f = x;
  unsigned r = v.u + 0x7fffu + ((v.u >> 16) & 1u);   // RNE
  return (unsigned short)(r >> 16);
}
__device__ __forceinline__ float bf2f(unsigned short b) {
  union { unsigned u; float f; } v; v.u = ((unsigned)b) << 16; return v.f;
}
__device__ __forceinline__ float sigm(float v) { return 1.f / (1.f + __expf(-v)); }
__device__ __forceinline__ float tanh_(float v) { return 1.f - 2.f / (__expf(2.f * v) + 1.f); }

// ---------------- prep: LSTM hi-only row-major; dense interleaved hi/lo ---------------
__global__ void prep_k(const float* __restrict__ Whh0, const float* __restrict__ Wih1,
                       const float* __restrict__ Whh1, const float* __restrict__ Wd0,
                       const float* __restrict__ Wd1, const float* __restrict__ Wd2,
                       const float* __restrict__ Wout, unsigned short* __restrict__ ws) {
  int id = blockIdx.x * 256 + threadIdx.x;
  if (id >= 397312) return;
  if (id < 65536) {                       // W_hh_l0 [512][128] hi-only
    ws[OFF_HH0 + id] = f2bf(Whh0[id]);
    return;
  }
  if (id < 196608) {                      // B_l1 [512][256] = cat(Wih1,Whh1) hi-only
    int i = id - 65536;
    int r = i >> 8, k = i & 255;
    float w = (k < 128) ? Wih1[(r << 7) + k] : Whh1[(r << 7) + k - 128];
    ws[OFF_L1 + i] = f2bf(w);
    return;
  }
  float w; int base, r, k;
  if (id < 262144) {                      // Bd0 [256][256], permute: our k<128 = mean
    int i = id - 196608; r = i >> 8; k = i & 255; base = OFF_D0;
    w = Wd0[(r << 8) + ((k < 128) ? k + 128 : k - 128)];
  } else if (id < 327680) {               // Bd1
    int i = id - 262144; r = i >> 8; k = i & 255; base = OFF_D1; w = Wd1[i];
  } else if (id < 393216) {               // Bd2
    int i = id - 327680; r = i >> 8; k = i & 255; base = OFF_D2; w = Wd2[i];
  } else {                                // Bout [16][256], rows >=4 zero
    int i = id - 393216; r = i >> 8; k = i & 255; base = OFF_OUT;
    w = (r < 4) ? Wout[(r << 8) + k] : 0.f;
  }
  unsigned short hi = f2bf(w);
  unsigned short lo = f2bf(w - bf2f(hi));
  int off = base + r * 512 + ((k >> 3) << 4) + (k & 7);
  ws[off] = hi;
  ws[off + 8] = lo;
}

// ------- 1-term GEMM (LSTM): B hi-only row-major, A hi-only, acc += Ah*Bh -------
template <int NT, int KITERS, int UNROLL>
__device__ __forceinline__ void gemm1t(const unsigned short* __restrict__ B,
                                       const int ldB, const int* cols,
                                       const unsigned short (*Ah)[AS],
                                       int l16, int quad, f32x4 (&acc)[4][4]) {
  const unsigned short* bp[NT];
#pragma unroll
  for (int n = 0; n < NT; ++n)
    bp[n] = B + (size_t)(cols[n] + l16) * ldB + quad * 8;
  const unsigned short* aph = &Ah[l16][quad * 8];
#pragma unroll UNROLL
  for (int ki = 0; ki < KITERS; ++ki) {
    bf16x8 bh[NT];
#pragma unroll
    for (int n = 0; n < NT; ++n) {
      bh[n] = *(const bf16x8*)(bp[n]);
      bp[n] += 32;
    }
    bf16x8 afh[4];
#pragma unroll
    for (int m = 0; m < 4; ++m)
      afh[m] = *(const bf16x8*)(aph + m * 16 * AS);
#pragma unroll
    for (int n = 0; n < NT; ++n)
#pragma unroll
      for (int m = 0; m < 4; ++m)
        acc[m][n] = __builtin_amdgcn_mfma_f32_16x16x32_bf16(afh[m], bh[n], acc[m][n], 0, 0, 0);
    aph += 32;
  }
}

// ------- 3-term split GEMM (dense): interleaved hi/lo B -------
template <int NT, int KITERS, int UNROLL>
__device__ __forceinline__ void gemm3t(const unsigned short* __restrict__ B,
                                       const int ldB2, const int* cols,
                                       const unsigned short (*Ah)[AS],
                                       const unsigned short (*Al)[AS],
                                       int l16, int quad, f32x4 (&acc)[4][4]) {
  const unsigned short* bp[NT];
#pragma unroll
  for (int n = 0; n < NT; ++n)
    bp[n] = B + (size_t)(cols[n] + l16) * ldB2 + quad * 16;
  const unsigned short* aph = &Ah[l16][quad * 8];
  const unsigned short* apl = &Al[l16][quad * 8];
#pragma unroll UNROLL
  for (int ki = 0; ki < KITERS; ++ki) {
    bf16x8 bh[NT], bl[NT];
#pragma unroll
    for (int n = 0; n < NT; ++n) {
      bh[n] = *(const bf16x8*)(bp[n]);
      bl[n] = *(const bf16x8*)(bp[n] + 8);
      bp[n] += 64;
    }
    bf16x8 afh[4], afl[4];
#pragma unroll
    for (int m = 0; m < 4; ++m) {
      afh[m] = *(const bf16x8*)(aph + m * 16 * AS);
      afl[m] = *(const bf16x8*)(apl + m * 16 * AS);
    }
#pragma unroll
    for (int n = 0; n < NT; ++n)
#pragma unroll
      for (int m = 0; m < 4; ++m)
        acc[m][n] = __builtin_amdgcn_mfma_f32_16x16x32_bf16(afh[m], bh[n], acc[m][n], 0, 0, 0);
#pragma unroll
    for (int n = 0; n < NT; ++n)
#pragma unroll
      for (int m = 0; m < 4; ++m)
        acc[m][n] = __builtin_amdgcn_mfma_f32_16x16x32_bf16(afl[m], bh[n], acc[m][n], 0, 0, 0);
#pragma unroll
    for (int n = 0; n < NT; ++n)
#pragma unroll
      for (int m = 0; m < 4; ++m)
        acc[m][n] = __builtin_amdgcn_mfma_f32_16x16x32_bf16(afh[m], bl[n], acc[m][n], 0, 0, 0);
    aph += 32;
    apl += 32;
  }
}

// ---------------- main fused kernel: 1 block = 64 samples, 8 waves, full network -------
__global__ __launch_bounds__(512, 1) void fused_k(
    const float* __restrict__ x, const float* __restrict__ y,
    const float* __restrict__ Wih0, const float* __restrict__ b0,
    const float* __restrict__ b1, const float* __restrict__ bd0,
    const float* __restrict__ bd1, const float* __restrict__ bd2,
    const float* __restrict__ bout, const unsigned short* __restrict__ wsu,
    float* __restrict__ out) {
  // Double-buffered activation planes. Plane p=t&1 holds [h0_t | h1_{t-1}] for iter t.
  // Alo planes only used for the dense head (written at t=5 and by dense layers).
  __shared__ unsigned short Ahi[2][TM][AS];
  __shared__ unsigned short Alo[2][TM][AS];
  __shared__ float feats[6][TM];

  const int tid = threadIdx.x;
  const int wv = tid >> 6;     // wave 0..7
  const int lane = tid & 63;
  const int quad = lane >> 4;  // 0..3
  const int l16 = lane & 15;
  const int u = 16 * wv + l16; // this lane's LSTM unit (0..127)
  const int sb = blockIdx.x * TM;

  if (tid < TM) {
    float xn = 2.f * x[sb + tid] - 1.f;
    float yn = 2.f * y[sb + tid] - 1.f;
    feats[0][tid] = xn; feats[1][tid] = yn; feats[2][tid] = xn + yn;
    feats[3][tid] = xn - yn; feats[4][tid] = xn * yn; feats[5][tid] = xn * xn + yn * yn;
  }

  // per-lane weights/biases straight from global (L1/L2-hot): gate n -> col 128n+u
  float wih0v[4], b0v[4], b1v[4];
#pragma unroll
  for (int n = 0; n < 4; ++n) {
    wih0v[n] = Wih0[128 * n + u]; b0v[n] = b0[128 * n + u]; b1v[n] = b1[128 * n + u];
  }

  // per-lane state: [m][r] -> sample s=16m+4quad+r, unit u
  float c0[4][4], c1[4][4], meanh[4][4];
#pragma unroll
  for (int m = 0; m < 4; ++m)
#pragma unroll
    for (int r = 0; r < 4; ++r) { c0[m][r] = 0.f; c1[m][r] = 0.f; meanh[m][r] = 0.f; }

  int colsL[4];  // gate-type n -> col block
#pragma unroll
  for (int n = 0; n < 4; ++n) colsL[n] = 128 * n + 16 * wv;

  __syncthreads();  // feats visible

  f32x4 acc[4][4];

  // ---- prologue: pw0(t=0): gates = x_0*Wih0 + b0 (no GEMM), h0_0 -> plane 0 (hi) ----
#pragma unroll
  for (int m = 0; m < 4; ++m)
#pragma unroll
    for (int r = 0; r < 4; ++r) {
      const float xf = feats[0][16 * m + 4 * quad + r];
      float iv = sigm(xf * wih0v[0] + b0v[0]);
      float gv = tanh_(xf * wih0v[2] + b0v[2]);
      float ov = sigm(xf * wih0v[3] + b0v[3]);
      float cc = iv * gv;                // c was 0: f*0 + i*g
      c0[m][r] = cc;
      float h = ov * tanh_(cc);
      const int s = 16 * m + 4 * quad + r;
      Ahi[0][s][u] = f2bf(h);
    }

  // ---- main loop: one barrier per t. Plane p = t&1 holds [h0_t | h1_{t-1}]. ----
#pragma unroll 1
  for (int t = 0; t < 6; ++t) {
    const int p = t & 1;
    const int pn = p ^ 1;
    __syncthreads();  // h0_t (and h1_{t-1}) visible in plane p; WAR for plane pn writes

    // gemm1(t): gates1 = [h0_t ; h1_{t-1}] @ [Wih1;Whh1]^T + b1   (1-term)
#pragma unroll
    for (int m = 0; m < 4; ++m)
#pragma unroll
      for (int n = 0; n < 4; ++n)
#pragma unroll
        for (int r = 0; r < 4; ++r) acc[m][n][r] = b1v[n];
    if (t == 0)
      gemm1t<4, 4, 1>(wsu + OFF_L1, 256, colsL, Ahi[p], l16, quad, acc);
    else
      gemm1t<4, 8, 2>(wsu + OFF_L1, 256, colsL, Ahi[p], l16, quad, acc);

    // pw1(t): h1_t -> plane pn [128:256) (hi; +lo at t=5); mean at t=5 -> plane pn [0:128)
#pragma unroll
    for (int m = 0; m < 4; ++m)
#pragma unroll
      for (int r = 0; r < 4; ++r) {
        float iv = sigm(acc[m][0][r]);
        float fv = sigm(acc[m][1][r]);
        float gv = tanh_(acc[m][2][r]);
        float ov = sigm(acc[m][3][r]);
        float cc = fv * c1[m][r] + iv * gv;
        c1[m][r] = cc;
        float h = ov * tanh_(cc);
        const int s = 16 * m + 4 * quad + r;
        unsigned short hh = f2bf(h);
        Ahi[pn][s][128 + u] = hh;
        float mn = meanh[m][r] + h;
        meanh[m][r] = mn;
        if (t == 5) {
          Alo[pn][s][128 + u] = f2bf(h - bf2f(hh));   // "last" lo for dense 3-term
          mn *= (1.f / 6.f);
          unsigned short mh = f2bf(mn);
          Ahi[pn][s][u] = mh;
          Alo[pn][s][u] = f2bf(mn - bf2f(mh));
        }
      }

    if (t < 5) {
      // gemm0(t+1): gates0 = x_{t+1}*Wih0 + b0 (C-init) + h0_t @ Whh0^T   (1-term)
#pragma unroll
      for (int m = 0; m < 4; ++m)
#pragma unroll
        for (int r = 0; r < 4; ++r) {
          const float xf = feats[t + 1][16 * m + 4 * quad + r];
#pragma unroll
          for (int n = 0; n < 4; ++n) acc[m][n][r] = xf * wih0v[n] + b0v[n];
        }
      gemm1t<4, 4, 1>(wsu + OFF_HH0, 128, colsL, Ahi[p], l16, quad, acc);

      // pw0(t+1): h0_{t+1} -> plane pn [0:128) (hi only)
#pragma unroll
      for (int m = 0; m < 4; ++m)
#pragma unroll
        for (int r = 0; r < 4; ++r) {
          float iv = sigm(acc[m][0][r]);
          float fv = sigm(acc[m][1][r]);
          float gv = tanh_(acc[m][2][r]);
          float ov = sigm(acc[m][3][r]);
          float cc = fv * c0[m][r] + iv * gv;
          c0[m][r] = cc;
          float h = ov * tanh_(cc);
          const int s = 16 * m + 4 * quad + r;
          Ahi[pn][s][u] = f2bf(h);
        }
    }
  }

  // ---- dense head: 3 layers (3-term); L0 reads plane0=[mean|last] ----
  int colsD[2];
  colsD[0] = 32 * wv; colsD[1] = 32 * wv + 16;

#pragma unroll 1
  for (int layer = 0; layer < 3; ++layer) {
    const int base = (layer == 0) ? OFF_D0 : ((layer == 1) ? OFF_D1 : OFF_D2);
    const float* bd = (layer == 0) ? bd0 : ((layer == 1) ? bd1 : bd2);
    const int sp = layer & 1;   // read plane 0,1,0
    const int dp = sp ^ 1;
    float bdv[2];
#pragma unroll
    for (int n = 0; n < 2; ++n) bdv[n] = bd[colsD[n] + l16];
#pragma unroll
    for (int m = 0; m < 4; ++m)
#pragma unroll
      for (int n = 0; n < 2; ++n)
#pragma unroll
        for (int r = 0; r < 4; ++r) acc[m][n][r] = bdv[n];
    __syncthreads();  // prev writes visible; prev reads of dp done (WAR)
    gemm3t<2, 8, 2>(wsu + base, 512, colsD, Ahi[sp], Alo[sp], l16, quad, acc);
#pragma unroll
    for (int m = 0; m < 4; ++m)
#pragma unroll
      for (int r = 0; r < 4; ++r) {
        const int s = 16 * m + 4 * quad + r;
#pragma unroll
        for (int n = 0; n < 2; ++n) {
          const int col = colsD[n] + l16;
          float a = tanh_(acc[m][n][r]);
          unsigned short ah = f2bf(a);
          Ahi[dp][s][col] = ah;
          Alo[dp][s][col] = f2bf(a - bf2f(ah));
        }
      }
  }
  __syncthreads();

  // ---- output layer (3-term): waves 0..3 handle m-tile wv; read plane 1 ----
  if (wv < 4) {
    f32x4 oacc = {0.f, 0.f, 0.f, 0.f};
    const unsigned short* bp = wsu + OFF_OUT + (size_t)l16 * 512 + quad * 16;
    const unsigned short* aph = &Ahi[1][16 * wv + l16][quad * 8];
    const unsigned short* apl = &Alo[1][16 * wv + l16][quad * 8];
#pragma unroll 1
    for (int ki = 0; ki < 8; ++ki) {
      bf16x8 ah = *(const bf16x8*)aph;
      bf16x8 al = *(const bf16x8*)apl;
      bf16x8 bh = *(const bf16x8*)bp;
      bf16x8 bl = *(const bf16x8*)(bp + 8);
      oacc = __builtin_amdgcn_mfma_f32_16x16x32_bf16(ah, bh, oacc, 0, 0, 0);
      oacc = __builtin_amdgcn_mfma_f32_16x16x32_bf16(al, bh, oacc, 0, 0, 0);
      oacc = __builtin_amdgcn_mfma_f32_16x16x32_bf16(ah, bl, oacc, 0, 0, 0);
      aph += 32; apl += 32; bp += 64;
    }
    float bo = (l16 < 4) ? bout[l16] : 0.f;
#pragma unroll
    for (int r = 0; r < 4; ++r) {
      if (l16 < 4) {
        int s = sb + 16 * wv + 4 * quad + r;
        out[s * 4 + l16] = oacc[r] + bo;
      }
    }
  }
}

extern "C" void kernel_launch(void* const* d_in, const int* in_sizes, int n_in,
                              void* d_out, int out_size, void* d_ws, size_t ws_size,
                              hipStream_t stream) {
  (void)in_sizes; (void)n_in; (void)out_size; (void)ws_size;
  const float* x    = (const float*)d_in[0];
  const float* y    = (const float*)d_in[1];
  const float* Wih0 = (const float*)d_in[2];
  const float* Whh0 = (const float*)d_in[3];
  const float* b0   = (const float*)d_in[4];
  const float* Wih1 = (const float*)d_in[5];
  const float* Whh1 = (const float*)d_in[6];
  const float* b1   = (const float*)d_in[7];
  const float* Wd0  = (const float*)d_in[8];
  const float* bd0  = (const float*)d_in[9];
  const float* Wd1  = (const float*)d_in[10];
  const float* bd1  = (const float*)d_in[11];
  const float* Wd2  = (const float*)d_in[12];
  const float* bd2  = (const float*)d_in[13];
  const float* Wout = (const float*)d_in[14];
  const float* bout = (const float*)d_in[15];
  unsigned short* ws = (unsigned short*)d_ws;
  float* out = (float*)d_out;

  prep_k<<<dim3(1552), dim3(256), 0, stream>>>(Whh0, Wih1, Whh1, Wd0, Wd1, Wd2, Wout, ws);
  fused_k<<<dim3(65536 / TM), dim3(512), 0, stream>>>(x, y, Wih0, b0, b1, bd0, bd1, bd2,
                                                      bout, ws, out);
}